// Round 20
// baseline (155.563 us; speedup 1.0000x reference)
//
#include <hip/hip_runtime.h>
#include <math.h>

#define HEADS 4
#define NEG_SLOPE 0.2f
#define CAP 32   // bucket capacity per node (avg in-degree 8; P(deg>32) ~ 2e-11; clamp guards)

// ---------------- workspace layout (bytes) ----------------
static constexpr size_t OFF_H1B  = 0;
static constexpr size_t OFF_H2B  = 0;
static constexpr size_t OFF_OUT2 = 6400000;
static constexpr size_t OFF_O1HI = 25600000;
static constexpr size_t OFF_W1TH = 76800000;   // 256x128 bf16 = 64KB
static constexpr size_t OFF_W1TL = 76865536;
static constexpr size_t OFF_W2TH = 76931072;   // 64x256 bf16 = 32KB
static constexpr size_t OFF_W2TL = 76963840;
static constexpr size_t OFF_AS   = 77000000;   // 800,000
static constexpr size_t OFF_AD   = 77800000;   // 800,000
static constexpr size_t OFF_CNT  = 78600064;   // 2N ints
static constexpr size_t OFF_CSR  = 79000128;   // 2N*CAP ints = 12.8 MB

typedef __attribute__((ext_vector_type(8))) short short8;
typedef __attribute__((ext_vector_type(4))) float f32x4;

// ---------------- helpers ----------------
__device__ __forceinline__ float4 f4add(float4 a, float4 b) {
    return make_float4(a.x + b.x, a.y + b.y, a.z + b.z, a.w + b.w);
}
__device__ __forceinline__ float lrelu(float x) { return x > 0.f ? x : NEG_SLOPE * x; }
__device__ __forceinline__ float4 f4lrelu(float4 a) {
    return make_float4(lrelu(a.x), lrelu(a.y), lrelu(a.z), lrelu(a.w));
}
__device__ __forceinline__ float4 f4exp(float4 a) {
    return make_float4(__expf(a.x), __expf(a.y), __expf(a.z), __expf(a.w));
}
__device__ __forceinline__ float pickh(float4 v, int head) {
    float r = v.x;
    r = head == 1 ? v.y : r;
    r = head == 2 ? v.z : r;
    r = head == 3 ? v.w : r;
    return r;
}
__device__ __forceinline__ unsigned short bfr(float x) {
    union { float f; unsigned u; } c; c.f = x;
    unsigned r = c.u + 0x7FFFu + ((c.u >> 16) & 1u);
    return (unsigned short)(r >> 16);
}
__device__ __forceinline__ float bf2f(unsigned short h) {
    union { unsigned u; float f; } c; c.u = ((unsigned)h) << 16;
    return c.f;
}
__device__ __forceinline__ float2 bfpair(unsigned u) {
    union { unsigned a; float f; } lo, hi;
    lo.a = u << 16;
    hi.a = u & 0xffff0000u;
    return make_float2(lo.f, hi.f);
}

// ---------------- prep: W1T/W2T splits + cnt zero (x split moved into GEMM1) -----
__global__ void prep_kernel(const float* __restrict__ W1, unsigned short* __restrict__ w1th,
                            unsigned short* __restrict__ w1tl,
                            const float* __restrict__ W2, unsigned short* __restrict__ w2th,
                            unsigned short* __restrict__ w2tl,
                            int* __restrict__ cnt, int n2)
{
    const int b = blockIdx.x, t = threadIdx.x;
    if (b < 128) {
        int idx = b * 256 + t;                   // W1: K=128, N=256
        const int K = 128, Nc = 256;
        int k = idx / Nc, n = idx - k * Nc;
        float v = W1[idx];
        unsigned short h = bfr(v);
        w1th[(size_t)n * K + k] = h;
        w1tl[(size_t)n * K + k] = bfr(v - bf2f(h));
    } else if (b < 128 + 64) {
        int idx = (b - 128) * 256 + t;           // W2: K=256, N=64
        const int K = 256, Nc = 64;
        int k = idx / Nc, n = idx - k * Nc;
        float v = W2[idx];
        unsigned short h = bfr(v);
        w2th[(size_t)n * K + k] = h;
        w2tl[(size_t)n * K + k] = bfr(v - bf2f(h));
    } else {
        int idx = (b - 192) * 256 + t;           // zero cnt[2N] via int4
        if (idx < (n2 >> 2)) ((int4*)cnt)[idx] = make_int4(0, 0, 0, 0);
    }
}

// ---------------- FUSED1: layer-1 GEMM (f32 x, in-register split) || bucket-L1 ---
// Groups of 16 blocks: offsets 0-7 = GEMM, 8-15 = bucket layer-1 (part = b&7).
__global__ __launch_bounds__(256, 2)
void gemm1_bucket_kernel(const float* __restrict__ X,
                         const unsigned short* __restrict__ BThi, const unsigned short* __restrict__ BTlo,
                         unsigned short* __restrict__ Cb,
                         const float* __restrict__ avec_s, const float* __restrict__ avec_d,
                         float* __restrict__ alpha_s, float* __restrict__ alpha_d,
                         int M, int N, int GX, int NCHUNK,
                         const int* __restrict__ src1, const int* __restrict__ dst1,
                         int* __restrict__ cnt, int* __restrict__ csr, int E)
{
    constexpr int BM = 64, BN = 128, KDIM = 128, WC = 2, CPH = 64;
    constexpr int BK = 32;
    constexpr int WROWS = 32, WCOLS = 64, FR = 2, FC = 4, BP = 2;

    __shared__ short As_hi[BM * BK], As_lo[BM * BK];
    __shared__ short Bs_hi[BN * BK], Bs_lo[BN * BK];

    const int group = blockIdx.x / 16;
    const int off   = blockIdx.x % 16;
    const int GEMM_CNT = GX * 2;

    if (off >= 8) {
        // ---------------- bucket layer-1 block ----------------
        const int part  = blockIdx.x & 7;
        const int chunk = group;
        if (chunk >= NCHUNK) return;
        const int base = chunk * 2048 + threadIdx.x;
#pragma unroll
        for (int k = 0; k < 8; ++k) {
            int e = base + k * 256;
            if (e < E) {
                int d = dst1[e];
                if ((d & 7) == part) {
                    int p = atomicAdd(&cnt[d], 1);
                    if (p < CAP) csr[(size_t)d * CAP + p] = src1[e];
                }
            }
        }
        return;
    }

    // ---------------- GEMM block ----------------
    const int gid = group * 8 + off;
    if (gid >= GEMM_CNT) return;
    const int bx = gid % GX, by = gid / GX;
    const int tid  = threadIdx.x;
    const int w    = tid >> 6, lane = tid & 63;
    const int wr   = w / WC, wc = w % WC;
    const int lrow = lane & 15, lk = lane >> 4;
    const int m0   = bx * BM, n0 = by * BN;

    f32x4 acc[FR][FC];
#pragma unroll
    for (int i = 0; i < FR; ++i)
#pragma unroll
        for (int j = 0; j < FC; ++j) acc[i][j] = (f32x4){0.f, 0.f, 0.f, 0.f};

    short8 rAh, rAl;
    short8 rBh[BP], rBl[BP];

    auto LOAD = [&](int kb) {
        {
            int r = tid >> 2, c = tid & 3;
            int row = m0 + r; row = row < M ? row : M - 1;
            const float* xp = X + (size_t)row * KDIM + kb + c * 8;
            float4 v0 = *(const float4*)xp;
            float4 v1 = *(const float4*)(xp + 4);
            float vv[8] = {v0.x, v0.y, v0.z, v0.w, v1.x, v1.y, v1.z, v1.w};
#pragma unroll
            for (int k = 0; k < 8; ++k) {
                unsigned short h = bfr(vv[k]);
                rAh[k] = (short)h;
                rAl[k] = (short)bfr(vv[k] - bf2f(h));
            }
        }
#pragma unroll
        for (int p = 0; p < BP; ++p) {
            int id = p * 256 + tid;
            int r = id >> 2, c = id & 3;
            size_t offb = (size_t)(n0 + r) * KDIM + kb + c * 8;
            rBh[p] = *(const short8*)(BThi + offb);
            rBl[p] = *(const short8*)(BTlo + offb);
        }
    };
    auto STORE = [&]() {
        {
            int r = tid >> 2, c = tid & 3;
            *(short8*)(&As_hi[r * BK + c * 8]) = rAh;
            *(short8*)(&As_lo[r * BK + c * 8]) = rAl;
        }
#pragma unroll
        for (int p = 0; p < BP; ++p) {
            int id = p * 256 + tid;
            int r = id >> 2, c = id & 3;
            *(short8*)(&Bs_hi[r * BK + c * 8]) = rBh[p];
            *(short8*)(&Bs_lo[r * BK + c * 8]) = rBl[p];
        }
    };

    constexpr int NT = KDIM / BK;
    LOAD(0);
    for (int t = 0; t < NT; ++t) {
        STORE();
        __syncthreads();
        if (t + 1 < NT) LOAD((t + 1) * BK);

        short8 afh[FR], afl[FR], bfh[FC], bfl[FC];
#pragma unroll
        for (int fr = 0; fr < FR; ++fr) {
            int r = wr * WROWS + fr * 16 + lrow;
            afh[fr] = *(const short8*)(&As_hi[r * BK + lk * 8]);
            afl[fr] = *(const short8*)(&As_lo[r * BK + lk * 8]);
        }
#pragma unroll
        for (int fc = 0; fc < FC; ++fc) {
            int r = wc * WCOLS + fc * 16 + lrow;
            bfh[fc] = *(const short8*)(&Bs_hi[r * BK + lk * 8]);
            bfl[fc] = *(const short8*)(&Bs_lo[r * BK + lk * 8]);
        }
#pragma unroll
        for (int fr = 0; fr < FR; ++fr)
#pragma unroll
            for (int fc = 0; fc < FC; ++fc) {
                acc[fr][fc] = __builtin_amdgcn_mfma_f32_16x16x32_bf16(afh[fr], bfh[fc], acc[fr][fc], 0, 0, 0);
                acc[fr][fc] = __builtin_amdgcn_mfma_f32_16x16x32_bf16(afh[fr], bfl[fc], acc[fr][fc], 0, 0, 0);
                acc[fr][fc] = __builtin_amdgcn_mfma_f32_16x16x32_bf16(afl[fr], bfh[fc], acc[fr][fc], 0, 0, 0);
            }
        __syncthreads();
    }

#pragma unroll
    for (int fr = 0; fr < FR; ++fr) {
        const int rbase = m0 + wr * WROWS + fr * 16 + lk * 4;
        float ps[4] = {0.f, 0.f, 0.f, 0.f}, pd[4] = {0.f, 0.f, 0.f, 0.f};
#pragma unroll
        for (int fc = 0; fc < FC; ++fc) {
            const int gc   = n0 + wc * WCOLS + fc * 16 + lrow;
            const int head = gc / CPH, ci = gc % CPH;
            const float asv = avec_s[head * CPH + ci];
            const float adv = avec_d[head * CPH + ci];
#pragma unroll
            for (int rg = 0; rg < 4; ++rg) {
                int row = rbase + rg;
                float v = acc[fr][fc][rg];
                unsigned short uh = bfr(v);
                unsigned up = (unsigned)__shfl_xor((int)(unsigned)uh, 1);
                if (!(lrow & 1) && row < M)
                    *(unsigned*)(Cb + (size_t)row * N + gc) = (unsigned)uh | (up << 16);
                ps[rg] += v * asv;
                pd[rg] += v * adv;
            }
        }
        const int head = (n0 + wc * WCOLS) / CPH;
#pragma unroll
        for (int rg = 0; rg < 4; ++rg) {
            float s = ps[rg], d = pd[rg];
#pragma unroll
            for (int m = 1; m <= 8; m <<= 1) {
                s += __shfl_xor(s, m);
                d += __shfl_xor(d, m);
            }
            if (lrow == 0 && rbase + rg < M) {
                alpha_s[(size_t)(rbase + rg) * HEADS + head] = s;
                alpha_d[(size_t)(rbase + rg) * HEADS + head] = d;
            }
        }
    }
}

// ---------------- FUSED2: layer-1 aggregation || bucket-L2 ----------------
// Groups of 40 blocks: offsets 0-31 = agg1 (8 nodes/block), 32-39 = bucket
// layer-2 (part = b&7; 40%8==0 keeps affinity). Disjoint data: agg reads
// layer-1 buckets, bucket writes layer-2 buckets.
__global__ __launch_bounds__(256)
void agg1_bucket_kernel(const unsigned short* __restrict__ hb, const float* __restrict__ alpha_s,
                        const float* __restrict__ alpha_d, const int* __restrict__ cnt,
                        const int* __restrict__ csr, const float* __restrict__ bias,
                        unsigned short* __restrict__ out_hi, int n, int NCHUNK,
                        const int* __restrict__ src2, const int* __restrict__ dst2,
                        int* __restrict__ cnt2, int* __restrict__ csr2, int E)
{
    constexpr int CH = 256, S = 32, CPL = 8, NSG = 8;
    __shared__ float wls[NSG][S * 5];

    const int group = blockIdx.x / 40;
    const int off   = blockIdx.x % 40;

    if (off >= 32) {
        // ---------------- bucket layer-2 block ----------------
        const int part  = blockIdx.x & 7;
        const int chunk = group;
        if (chunk >= NCHUNK) return;
        const int base = chunk * 2048 + threadIdx.x;
#pragma unroll
        for (int k = 0; k < 8; ++k) {
            int e = base + k * 256;
            if (e < E) {
                int d = dst2[e];
                if ((d & 7) == part) {
                    int p = atomicAdd(&cnt2[d], 1);
                    if (p < CAP) csr2[(size_t)d * CAP + p] = src2[e];
                }
            }
        }
        return;
    }

    // ---------------- agg1 block ----------------
    const int gid = group * 32 + off;
    const int tid    = threadIdx.x;
    const int sub    = tid / S;
    const int i      = tid % S;
    const int lane64 = tid & 63;
    const int base   = lane64 & ~(S - 1);
    const int node   = gid * NSG + sub;
    if (node >= n) return;
    const int head = (i * CPL) / (CH / 4);
    const int deg = min(cnt[node], CAP);
    const size_t ebase = (size_t)node * CAP;

    const float4 asn = *(const float4*)(alpha_s + (size_t)node * 4);
    const float4 adn = *(const float4*)(alpha_d + (size_t)node * 4);
    float4 den = f4exp(f4lrelu(f4add(asn, adn)));
    const float wse = pickh(den, head);

    float acc[8];
    {
        uint4 hv = *(const uint4*)(hb + (size_t)node * CH + i * 8);
        float2 q0 = bfpair(hv.x), q1 = bfpair(hv.y), q2 = bfpair(hv.z), q3 = bfpair(hv.w);
        acc[0] = wse * q0.x; acc[1] = wse * q0.y; acc[2] = wse * q1.x; acc[3] = wse * q1.y;
        acc[4] = wse * q2.x; acc[5] = wse * q2.y; acc[6] = wse * q3.x; acc[7] = wse * q3.y;
    }

    for (int ch = 0; ch < deg; ch += S) {
        const int cntc = min(S, deg - ch);
        float4 w4 = make_float4(0.f, 0.f, 0.f, 0.f);
        int sl = 0;
        if (i < cntc) {
            sl = csr[ebase + ch + i];
            float4 al = *(const float4*)(alpha_s + (size_t)sl * 4);
            w4 = f4exp(f4lrelu(f4add(al, adn)));
        }
        float4 t = w4;
#pragma unroll
        for (int d = S / 2; d >= 1; d >>= 1) {
            t.x += __shfl_xor(t.x, d);
            t.y += __shfl_xor(t.y, d);
            t.z += __shfl_xor(t.z, d);
            t.w += __shfl_xor(t.w, d);
        }
        den = f4add(den, t);
        wls[sub][i * 5 + 0] = w4.x;
        wls[sub][i * 5 + 1] = w4.y;
        wls[sub][i * 5 + 2] = w4.z;
        wls[sub][i * 5 + 3] = w4.w;

        const int padded = (cntc + 7) & ~7;
        for (int j = 0; j < padded; j += 8) {
            int   sk[8];
            float wk[8];
#pragma unroll
            for (int k = 0; k < 8; ++k) {
                sk[k] = __shfl(sl, base + ((j + k) < S ? (j + k) : 0));
                wk[k] = wls[sub][(j + k) * 5 + head];
            }
            uint4 v[8];
#pragma unroll
            for (int k = 0; k < 8; ++k)
                v[k] = *(const uint4*)(hb + (size_t)sk[k] * CH + i * 8);
#pragma unroll
            for (int k = 0; k < 8; ++k) {
                float2 q0 = bfpair(v[k].x), q1 = bfpair(v[k].y);
                float2 q2 = bfpair(v[k].z), q3 = bfpair(v[k].w);
                acc[0] += wk[k] * q0.x; acc[1] += wk[k] * q0.y;
                acc[2] += wk[k] * q1.x; acc[3] += wk[k] * q1.y;
                acc[4] += wk[k] * q2.x; acc[5] += wk[k] * q2.y;
                acc[6] += wk[k] * q3.x; acc[7] += wk[k] * q3.y;
            }
        }
    }

    const float invd = 1.0f / (pickh(den, head) + 1e-16f);
    const int c0 = i * CPL;
    float o[8];
    unsigned short oh[8];
#pragma unroll
    for (int k = 0; k < 8; ++k) {
        o[k] = fmaxf(acc[k] * invd + bias[c0 + k], 0.f);
        oh[k] = bfr(o[k]);
    }
    uint4 ph;
    ph.x = (unsigned)oh[0] | ((unsigned)oh[1] << 16);
    ph.y = (unsigned)oh[2] | ((unsigned)oh[3] << 16);
    ph.z = (unsigned)oh[4] | ((unsigned)oh[5] << 16);
    ph.w = (unsigned)oh[6] | ((unsigned)oh[7] << 16);
    *(uint4*)(out_hi + (size_t)node * CH + c0) = ph;
}

// ---------------- MFMA GEMM template (layer 2) ----------------
template<int BM, int BN, int KDIM, int WR, int WC, int CPH, bool ALO>
__global__ __launch_bounds__(256, 2)
void mfma_gemm_gat(const unsigned short* __restrict__ Ahi, const unsigned short* __restrict__ Alo,
                   const unsigned short* __restrict__ BThi, const unsigned short* __restrict__ BTlo,
                   unsigned short* __restrict__ Cb,
                   const float* __restrict__ avec_s, const float* __restrict__ avec_d,
                   float* __restrict__ alpha_s, float* __restrict__ alpha_d,
                   int M, int N)
{
    constexpr int BK    = 32;
    constexpr int WROWS = BM / WR;
    constexpr int WCOLS = BN / WC;
    constexpr int FR    = WROWS / 16;
    constexpr int FC    = WCOLS / 16;
    constexpr int AP    = (BM * (BK / 8)) / 256;
    constexpr int BP    = (BN * (BK / 8)) / 256;
    static_assert(AP >= 1 && BP >= 1, "tile too small");

    __shared__ short As_hi[BM * BK], As_lo[ALO ? BM * BK : 64];
    __shared__ short Bs_hi[BN * BK], Bs_lo[BN * BK];

    const int tid  = threadIdx.x;
    const int w    = tid >> 6, lane = tid & 63;
    const int wr   = w / WC, wc = w % WC;
    const int lrow = lane & 15, lk = lane >> 4;
    const int m0   = blockIdx.x * BM, n0 = blockIdx.y * BN;

    f32x4 acc[FR][FC];
#pragma unroll
    for (int i = 0; i < FR; ++i)
#pragma unroll
        for (int j = 0; j < FC; ++j) acc[i][j] = (f32x4){0.f, 0.f, 0.f, 0.f};

    short8 rAh[AP], rAl[AP], rBh[BP], rBl[BP];

    auto LOAD = [&](int kb) {
#pragma unroll
        for (int p = 0; p < AP; ++p) {
            int id = p * 256 + tid;
            int r = id >> 2, c = id & 3;
            int row = m0 + r; row = row < M ? row : M - 1;
            size_t off = (size_t)row * KDIM + kb + c * 8;
            rAh[p] = *(const short8*)(Ahi + off);
            if constexpr (ALO) rAl[p] = *(const short8*)(Alo + off);
        }
#pragma unroll
        for (int p = 0; p < BP; ++p) {
            int id = p * 256 + tid;
            int r = id >> 2, c = id & 3;
            size_t off = (size_t)(n0 + r) * KDIM + kb + c * 8;
            rBh[p] = *(const short8*)(BThi + off);
            rBl[p] = *(const short8*)(BTlo + off);
        }
    };
    auto STORE = [&]() {
#pragma unroll
        for (int p = 0; p < AP; ++p) {
            int id = p * 256 + tid;
            int r = id >> 2, c = id & 3;
            *(short8*)(&As_hi[r * BK + c * 8]) = rAh[p];
            if constexpr (ALO) *(short8*)(&As_lo[r * BK + c * 8]) = rAl[p];
        }
#pragma unroll
        for (int p = 0; p < BP; ++p) {
            int id = p * 256 + tid;
            int r = id >> 2, c = id & 3;
            *(short8*)(&Bs_hi[r * BK + c * 8]) = rBh[p];
            *(short8*)(&Bs_lo[r * BK + c * 8]) = rBl[p];
        }
    };

    constexpr int NT = KDIM / BK;
    LOAD(0);
    for (int t = 0; t < NT; ++t) {
        STORE();
        __syncthreads();
        if (t + 1 < NT) LOAD((t + 1) * BK);

        short8 afh[FR], afl[FR], bfh[FC], bfl[FC];
#pragma unroll
        for (int fr = 0; fr < FR; ++fr) {
            int r = wr * WROWS + fr * 16 + lrow;
            afh[fr] = *(const short8*)(&As_hi[r * BK + lk * 8]);
            if constexpr (ALO) afl[fr] = *(const short8*)(&As_lo[r * BK + lk * 8]);
        }
#pragma unroll
        for (int fc = 0; fc < FC; ++fc) {
            int r = wc * WCOLS + fc * 16 + lrow;
            bfh[fc] = *(const short8*)(&Bs_hi[r * BK + lk * 8]);
            bfl[fc] = *(const short8*)(&Bs_lo[r * BK + lk * 8]);
        }
#pragma unroll
        for (int fr = 0; fr < FR; ++fr)
#pragma unroll
            for (int fc = 0; fc < FC; ++fc) {
                acc[fr][fc] = __builtin_amdgcn_mfma_f32_16x16x32_bf16(afh[fr], bfh[fc], acc[fr][fc], 0, 0, 0);
                acc[fr][fc] = __builtin_amdgcn_mfma_f32_16x16x32_bf16(afh[fr], bfl[fc], acc[fr][fc], 0, 0, 0);
                if constexpr (ALO)
                    acc[fr][fc] = __builtin_amdgcn_mfma_f32_16x16x32_bf16(afl[fr], bfh[fc], acc[fr][fc], 0, 0, 0);
            }
        __syncthreads();
    }

#pragma unroll
    for (int fr = 0; fr < FR; ++fr) {
        const int rbase = m0 + wr * WROWS + fr * 16 + lk * 4;
        float ps[4] = {0.f, 0.f, 0.f, 0.f}, pd[4] = {0.f, 0.f, 0.f, 0.f};
#pragma unroll
        for (int fc = 0; fc < FC; ++fc) {
            const int gc   = n0 + wc * WCOLS + fc * 16 + lrow;
            const int head = gc / CPH, ci = gc % CPH;
            const float asv = avec_s[head * CPH + ci];
            const float adv = avec_d[head * CPH + ci];
#pragma unroll
            for (int rg = 0; rg < 4; ++rg) {
                int row = rbase + rg;
                float v = acc[fr][fc][rg];
                unsigned short uh = bfr(v);
                unsigned up = (unsigned)__shfl_xor((int)(unsigned)uh, 1);
                if (!(lrow & 1) && row < M)
                    *(unsigned*)(Cb + (size_t)row * N + gc) = (unsigned)uh | (up << 16);
                ps[rg] += v * asv;
                pd[rg] += v * adv;
            }
            if constexpr (CPH == 16) {
#pragma unroll
                for (int rg = 0; rg < 4; ++rg) {
                    float s = ps[rg], d = pd[rg];
#pragma unroll
                    for (int m = 1; m <= 8; m <<= 1) {
                        s += __shfl_xor(s, m);
                        d += __shfl_xor(d, m);
                    }
                    if (lrow == 0 && rbase + rg < M) {
                        alpha_s[(size_t)(rbase + rg) * HEADS + head] = s;
                        alpha_d[(size_t)(rbase + rg) * HEADS + head] = d;
                    }
                    ps[rg] = 0.f; pd[rg] = 0.f;
                }
            }
        }
        if constexpr (CPH != 16) {
            const int head = (n0 + wc * WCOLS) / CPH;
#pragma unroll
            for (int rg = 0; rg < 4; ++rg) {
                float s = ps[rg], d = pd[rg];
#pragma unroll
                for (int m = 1; m <= 8; m <<= 1) {
                    s += __shfl_xor(s, m);
                    d += __shfl_xor(d, m);
                }
                if (lrow == 0 && rbase + rg < M) {
                    alpha_s[(size_t)(rbase + rg) * HEADS + head] = s;
                    alpha_d[(size_t)(rbase + rg) * HEADS + head] = d;
                }
            }
        }
    }
}

// ---------------- GAT aggregation (bucket CSR), standalone for layer 2 ----------
template<int CH, int S, bool OUTF32>
__global__ __launch_bounds__(256)
void gat_agg(const unsigned short* __restrict__ hb, const float* __restrict__ alpha_s,
             const float* __restrict__ alpha_d, const int* __restrict__ cnt,
             const int* __restrict__ csr, const float* __restrict__ bias,
             float* __restrict__ out, unsigned short* __restrict__ out_hi, int n)
{
    constexpr int CPL = CH / S;
    constexpr int NSG = 256 / S;
    static_assert(CPL == 8, "lane owns one uint4");
    __shared__ float wls[NSG][S * 5];
    const int tid    = threadIdx.x;
    const int sub    = tid / S;
    const int i      = tid % S;
    const int lane64 = tid & 63;
    const int base   = lane64 & ~(S - 1);
    const int node   = blockIdx.x * NSG + sub;
    if (node >= n) return;
    const int head = (i * CPL) / (CH / 4);
    const int deg = min(cnt[node], CAP);
    const size_t ebase = (size_t)node * CAP;

    const float4 asn = *(const float4*)(alpha_s + (size_t)node * 4);
    const float4 adn = *(const float4*)(alpha_d + (size_t)node * 4);
    float4 den = f4exp(f4lrelu(f4add(asn, adn)));
    const float wse = pickh(den, head);

    float acc[8];
    {
        uint4 hv = *(const uint4*)(hb + (size_t)node * CH + i * 8);
        float2 q0 = bfpair(hv.x), q1 = bfpair(hv.y), q2 = bfpair(hv.z), q3 = bfpair(hv.w);
        acc[0] = wse * q0.x; acc[1] = wse * q0.y; acc[2] = wse * q1.x; acc[3] = wse * q1.y;
        acc[4] = wse * q2.x; acc[5] = wse * q2.y; acc[6] = wse * q3.x; acc[7] = wse * q3.y;
    }

    for (int ch = 0; ch < deg; ch += S) {
        const int cntc = min(S, deg - ch);
        float4 w4 = make_float4(0.f, 0.f, 0.f, 0.f);
        int sl = 0;
        if (i < cntc) {
            sl = csr[ebase + ch + i];
            float4 al = *(const float4*)(alpha_s + (size_t)sl * 4);
            w4 = f4exp(f4lrelu(f4add(al, adn)));
        }
        float4 t = w4;
#pragma unroll
        for (int d = S / 2; d >= 1; d >>= 1) {
            t.x += __shfl_xor(t.x, d);
            t.y += __shfl_xor(t.y, d);
            t.z += __shfl_xor(t.z, d);
            t.w += __shfl_xor(t.w, d);
        }
        den = f4add(den, t);
        wls[sub][i * 5 + 0] = w4.x;
        wls[sub][i * 5 + 1] = w4.y;
        wls[sub][i * 5 + 2] = w4.z;
        wls[sub][i * 5 + 3] = w4.w;

        const int padded = (cntc + 7) & ~7;
        for (int j = 0; j < padded; j += 8) {
            int   sk[8];
            float wk[8];
#pragma unroll
            for (int k = 0; k < 8; ++k) {
                sk[k] = __shfl(sl, base + ((j + k) < S ? (j + k) : 0));
                wk[k] = wls[sub][(j + k) * 5 + head];
            }
            uint4 v[8];
#pragma unroll
            for (int k = 0; k < 8; ++k)
                v[k] = *(const uint4*)(hb + (size_t)sk[k] * CH + i * 8);
#pragma unroll
            for (int k = 0; k < 8; ++k) {
                float2 q0 = bfpair(v[k].x), q1 = bfpair(v[k].y);
                float2 q2 = bfpair(v[k].z), q3 = bfpair(v[k].w);
                acc[0] += wk[k] * q0.x; acc[1] += wk[k] * q0.y;
                acc[2] += wk[k] * q1.x; acc[3] += wk[k] * q1.y;
                acc[4] += wk[k] * q2.x; acc[5] += wk[k] * q2.y;
                acc[6] += wk[k] * q3.x; acc[7] += wk[k] * q3.y;
            }
        }
    }

    const float invd = 1.0f / (pickh(den, head) + 1e-16f);
    const int c0 = i * CPL;
    float o[8];
#pragma unroll
    for (int k = 0; k < 8; ++k)
        o[k] = fmaxf(acc[k] * invd + bias[c0 + k], 0.f);
    if constexpr (OUTF32) {
        *(float4*)(out + (size_t)node * CH + c0)     = make_float4(o[0], o[1], o[2], o[3]);
        *(float4*)(out + (size_t)node * CH + c0 + 4) = make_float4(o[4], o[5], o[6], o[7]);
    } else {
        unsigned short oh[8];
#pragma unroll
        for (int k = 0; k < 8; ++k) oh[k] = bfr(o[k]);
        uint4 ph;
        ph.x = (unsigned)oh[0] | ((unsigned)oh[1] << 16);
        ph.y = (unsigned)oh[2] | ((unsigned)oh[3] << 16);
        ph.z = (unsigned)oh[4] | ((unsigned)oh[5] << 16);
        ph.w = (unsigned)oh[6] | ((unsigned)oh[7] << 16);
        *(uint4*)(out_hi + (size_t)node * CH + c0) = ph;
    }
}

// ---------------- fused mean-pool/FC (per-block binary search) ----------------
__global__ __launch_bounds__(256)
void pool_fc_kernel(const float* __restrict__ feat, const int* __restrict__ batch,
                    const float* __restrict__ Wfc, const float* __restrict__ bfc,
                    float* __restrict__ out, int n)
{
    __shared__ float4 part[16][16];
    __shared__ float pooled[64];
    __shared__ int sb[2];
    const int g = blockIdx.x;
    const int t = threadIdx.x;
    if (t < 2) {
        int target = g + t;
        int lo = 0, hi = n;
        while (lo < hi) {
            int mid = (lo + hi) >> 1;
            if (batch[mid] < target) lo = mid + 1; else hi = mid;
        }
        sb[t] = lo;
    }
    __syncthreads();
    const int s0 = sb[0], s1 = sb[1];
    const int q = t & 15, ns = t >> 4;
    float4 acc = make_float4(0.f, 0.f, 0.f, 0.f);
    for (int i = s0 + ns; i < s1; i += 16)
        acc = f4add(acc, *(const float4*)(feat + (size_t)i * 64 + q * 4));
    part[ns][q] = acc;
    __syncthreads();
    if (t < 16) {
        float4 s = part[0][t];
#pragma unroll
        for (int k = 1; k < 16; ++k) s = f4add(s, part[k][t]);
        float inv = 1.0f / fmaxf((float)(s1 - s0), 1.0f);
        pooled[t * 4 + 0] = s.x * inv;
        pooled[t * 4 + 1] = s.y * inv;
        pooled[t * 4 + 2] = s.z * inv;
        pooled[t * 4 + 3] = s.w * inv;
    }
    __syncthreads();
    if (t < 2) {
        float a = bfc[t];
        for (int c = 0; c < 64; ++c) a += pooled[c] * Wfc[c * 2 + t];
        out[g * 2 + t] = a;
    }
}

// ---------------- launch ----------------
extern "C" void kernel_launch(void* const* d_in, const int* in_sizes, int n_in,
                              void* d_out, int out_size, void* d_ws, size_t ws_size,
                              hipStream_t stream)
{
    const float* x    = (const float*)d_in[0];
    const int*   ei   = (const int*)d_in[1];
    const int*   batch= (const int*)d_in[2];
    const float* W1   = (const float*)d_in[3];
    const float* as1  = (const float*)d_in[4];
    const float* ad1  = (const float*)d_in[5];
    const float* b1   = (const float*)d_in[6];
    const float* W2   = (const float*)d_in[7];
    const float* as2  = (const float*)d_in[8];
    const float* ad2  = (const float*)d_in[9];
    const float* b2   = (const float*)d_in[10];
    const float* Wfc  = (const float*)d_in[11];
    const float* bfc  = (const float*)d_in[12];
    float* out = (float*)d_out;

    const int N = in_sizes[2];          // 50000 nodes
    const int E = in_sizes[1] / 27;     // 400000 edges
    const int F = in_sizes[0] / N;      // 128

    char* ws = (char*)d_ws;
    unsigned short* h1b   = (unsigned short*)(ws + OFF_H1B);
    unsigned short* h2b   = (unsigned short*)(ws + OFF_H2B);
    float*          out2  = (float*)(ws + OFF_OUT2);
    unsigned short* o1hi  = (unsigned short*)(ws + OFF_O1HI);
    unsigned short* w1th  = (unsigned short*)(ws + OFF_W1TH);
    unsigned short* w1tl  = (unsigned short*)(ws + OFF_W1TL);
    unsigned short* w2th  = (unsigned short*)(ws + OFF_W2TH);
    unsigned short* w2tl  = (unsigned short*)(ws + OFF_W2TL);
    float* al_s  = (float*)(ws + OFF_AS);
    float* al_d  = (float*)(ws + OFF_AD);
    int*   cnt   = (int*)(ws + OFF_CNT);    // 2N counts (layer2 view = cnt+N)
    int*   csr   = (int*)(ws + OFF_CSR);    // 2N*CAP bucket table

    const int NCH1 = (E + 2047) / 2048;            // 196 layer-1 edge chunks
    const int ZB   = ((2 * N / 4) + 255) / 256;    // 98 zero-blocks in prep
    const int GX   = (N + 63) / 64;                // 782 gemm1 blocks per col-half

    // fused1: groups of 16 (8 GEMM + 8 bucket-L1)
    const int G1 = ((GX * 2 + 7) / 8 > NCH1) ? (GX * 2 + 7) / 8 : NCH1;   // 196
    // fused2: groups of 40 (32 agg1 + 8 bucket-L2)
    const int AGG_BLOCKS = (N + 7) / 8;                                    // 6250
    const int G2 = ((AGG_BLOCKS + 31) / 32 > NCH1) ? (AGG_BLOCKS + 31) / 32 : NCH1; // 196

    // ---- 1: prep (W splits + cnt zero) ----
    prep_kernel<<<192 + ZB, 256, 0, stream>>>(W1, w1th, w1tl, W2, w2th, w2tl, cnt, 2 * N);

    // ---- 2: FUSED layer-1 GEMM (f32 x) || bucket layer-1 ----
    gemm1_bucket_kernel<<<G1 * 16, 256, 0, stream>>>(
        x, w1th, w1tl, h1b, as1, ad1, al_s, al_d, N, HEADS * 64, GX, NCH1,
        ei + 17 * (size_t)E, ei + 26 * (size_t)E, cnt, csr, E);

    // ---- 3: FUSED layer-1 aggregation || bucket layer-2 ----
    agg1_bucket_kernel<<<G2 * 40, 256, 0, stream>>>(
        h1b, al_s, al_d, cnt, csr, b1, o1hi, N, NCH1,
        ei + 15 * (size_t)E, ei + 16 * (size_t)E,
        cnt + N, csr + (size_t)N * CAP, E);

    // ---- 4: layer-2 MFMA GEMM (bf16 A, 2-pass) -> bf16 h2 ----
    {
        dim3 g((N + 63) / 64, 1);
        mfma_gemm_gat<64, 64, 256, 2, 2, 16, false><<<g, 256, 0, stream>>>(
            o1hi, nullptr, w2th, w2tl, h2b, as2, ad2, al_s, al_d, N, HEADS * 16);
    }
    // ---- 5: layer-2 aggregation (S=8, 16B gathers, f32 out) ----
    gat_agg<64, 8, true><<<(N + 31) / 32, 256, 0, stream>>>(h2b, al_s, al_d, cnt + N,
                                                            csr + (size_t)N * CAP, b2,
                                                            out2, nullptr, N);

    // ---- 6: fused mean-pool + FC ----
    pool_fc_kernel<<<64, 256, 0, stream>>>(out2, batch, Wfc, bfc, out, N);
}

// Round 21
// 152.270 us; speedup vs baseline: 1.0216x; 1.0216x over previous
//
#include <hip/hip_runtime.h>
#include <math.h>

#define HEADS 4
#define NEG_SLOPE 0.2f
#define CAP 32   // bucket capacity per node (avg in-degree 8; P(deg>32) ~ 2e-11; clamp guards)

// ---------------- workspace layout (bytes) ----------------
static constexpr size_t OFF_H1B  = 0;
static constexpr size_t OFF_H2B  = 0;
static constexpr size_t OFF_OUT2 = 6400000;
static constexpr size_t OFF_O1HI = 25600000;
static constexpr size_t OFF_W1TH = 76800000;   // 256x128 bf16 = 64KB
static constexpr size_t OFF_W1TL = 76865536;
static constexpr size_t OFF_W2TH = 76931072;   // 64x256 bf16 = 32KB
static constexpr size_t OFF_W2TL = 76963840;
static constexpr size_t OFF_AS   = 77000000;   // 800,000
static constexpr size_t OFF_AD   = 77800000;   // 800,000
static constexpr size_t OFF_CNT  = 78600064;   // 2N ints
static constexpr size_t OFF_CSR  = 79000128;   // 2N*CAP ints = 12.8 MB

typedef __attribute__((ext_vector_type(8))) short short8;
typedef __attribute__((ext_vector_type(4))) float f32x4;

// ---------------- helpers ----------------
__device__ __forceinline__ float4 f4add(float4 a, float4 b) {
    return make_float4(a.x + b.x, a.y + b.y, a.z + b.z, a.w + b.w);
}
__device__ __forceinline__ float lrelu(float x) { return x > 0.f ? x : NEG_SLOPE * x; }
__device__ __forceinline__ float4 f4lrelu(float4 a) {
    return make_float4(lrelu(a.x), lrelu(a.y), lrelu(a.z), lrelu(a.w));
}
__device__ __forceinline__ float4 f4exp(float4 a) {
    return make_float4(__expf(a.x), __expf(a.y), __expf(a.z), __expf(a.w));
}
__device__ __forceinline__ float pickh(float4 v, int head) {
    float r = v.x;
    r = head == 1 ? v.y : r;
    r = head == 2 ? v.z : r;
    r = head == 3 ? v.w : r;
    return r;
}
__device__ __forceinline__ unsigned short bfr(float x) {
    union { float f; unsigned u; } c; c.f = x;
    unsigned r = c.u + 0x7FFFu + ((c.u >> 16) & 1u);
    return (unsigned short)(r >> 16);
}
__device__ __forceinline__ float bf2f(unsigned short h) {
    union { unsigned u; float f; } c; c.u = ((unsigned)h) << 16;
    return c.f;
}
__device__ __forceinline__ float2 bfpair(unsigned u) {
    union { unsigned a; float f; } lo, hi;
    lo.a = u << 16;
    hi.a = u & 0xffff0000u;
    return make_float2(lo.f, hi.f);
}

// ---------------- prep: W1T/W2T splits + cnt zero ----------------
__global__ void prep_kernel(const float* __restrict__ W1, unsigned short* __restrict__ w1th,
                            unsigned short* __restrict__ w1tl,
                            const float* __restrict__ W2, unsigned short* __restrict__ w2th,
                            unsigned short* __restrict__ w2tl,
                            int* __restrict__ cnt, int n2)
{
    const int b = blockIdx.x, t = threadIdx.x;
    if (b < 128) {
        int idx = b * 256 + t;                   // W1: K=128, N=256
        const int K = 128, Nc = 256;
        int k = idx / Nc, n = idx - k * Nc;
        float v = W1[idx];
        unsigned short h = bfr(v);
        w1th[(size_t)n * K + k] = h;
        w1tl[(size_t)n * K + k] = bfr(v - bf2f(h));
    } else if (b < 128 + 64) {
        int idx = (b - 128) * 256 + t;           // W2: K=256, N=64
        const int K = 256, Nc = 64;
        int k = idx / Nc, n = idx - k * Nc;
        float v = W2[idx];
        unsigned short h = bfr(v);
        w2th[(size_t)n * K + k] = h;
        w2tl[(size_t)n * K + k] = bfr(v - bf2f(h));
    } else {
        int idx = (b - 192) * 256 + t;           // zero cnt[2N] via int4
        if (idx < (n2 >> 2)) ((int4*)cnt)[idx] = make_int4(0, 0, 0, 0);
    }
}

// ---------------- FUSED + INTERLEAVED: layer-1 GEMM (f32 x) || bucket (both) -----
// Blocks in groups of 24: offsets 0-7 = GEMM, 8-23 = bucket (both layers).
// 24 % 8 == 0 keeps blockIdx%8 stable -> bucket partition (= blockIdx&7)
// retains XCD affinity; both populations co-resident from the start.
// GEMM half reads f32 x directly and splits to hi/lo bf16 in registers.
__global__ __launch_bounds__(256, 2)
void gemm1_bucket_kernel(const float* __restrict__ X,
                         const unsigned short* __restrict__ BThi, const unsigned short* __restrict__ BTlo,
                         unsigned short* __restrict__ Cb,
                         const float* __restrict__ avec_s, const float* __restrict__ avec_d,
                         float* __restrict__ alpha_s, float* __restrict__ alpha_d,
                         int M, int N, int GX, int NCHUNK,
                         const int* __restrict__ src1, const int* __restrict__ dst1,
                         const int* __restrict__ src2, const int* __restrict__ dst2,
                         int* __restrict__ cnt, int* __restrict__ csr, int NN, int E)
{
    constexpr int BM = 64, BN = 128, KDIM = 128, WC = 2, CPH = 64;
    constexpr int BK = 32;
    constexpr int WROWS = 32, WCOLS = 64, FR = 2, FC = 4, BP = 2;

    __shared__ short As_hi[BM * BK], As_lo[BM * BK];
    __shared__ short Bs_hi[BN * BK], Bs_lo[BN * BK];

    const int group = blockIdx.x / 24;
    const int off   = blockIdx.x % 24;
    const int GEMM_CNT = GX * 2;

    if (off >= 8) {
        // ---------------- bucket block (both layers) ----------------
        const int part  = blockIdx.x & 7;            // == off&7 (24*group ≡ 0 mod 8)
        const int chunk = group * 2 + (off >= 16);
        if (chunk >= NCHUNK) return;
        const int base = chunk * 2048 + threadIdx.x;
#pragma unroll
        for (int k = 0; k < 8; ++k) {
            int e = base + k * 256;
            if (e < E) {
                int d = dst1[e];
                if ((d & 7) == part) {
                    int p = atomicAdd(&cnt[d], 1);
                    if (p < CAP) csr[(size_t)d * CAP + p] = src1[e];
                }
            } else if (e < 2 * E) {
                int d = dst2[e - E];
                if ((d & 7) == part) {
                    int p = atomicAdd(&cnt[NN + d], 1);
                    if (p < CAP) csr[((size_t)NN + d) * CAP + p] = src2[e - E];
                }
            }
        }
        return;
    }

    // ---------------- GEMM block ----------------
    const int gid = group * 8 + off;
    if (gid >= GEMM_CNT) return;
    const int bx = gid % GX, by = gid / GX;
    const int tid  = threadIdx.x;
    const int w    = tid >> 6, lane = tid & 63;
    const int wr   = w / WC, wc = w % WC;
    const int lrow = lane & 15, lk = lane >> 4;
    const int m0   = bx * BM, n0 = by * BN;

    f32x4 acc[FR][FC];
#pragma unroll
    for (int i = 0; i < FR; ++i)
#pragma unroll
        for (int j = 0; j < FC; ++j) acc[i][j] = (f32x4){0.f, 0.f, 0.f, 0.f};

    short8 rAh, rAl;
    short8 rBh[BP], rBl[BP];

    auto LOAD = [&](int kb) {
        {
            int r = tid >> 2, c = tid & 3;
            int row = m0 + r; row = row < M ? row : M - 1;
            const float* xp = X + (size_t)row * KDIM + kb + c * 8;
            float4 v0 = *(const float4*)xp;
            float4 v1 = *(const float4*)(xp + 4);
            float vv[8] = {v0.x, v0.y, v0.z, v0.w, v1.x, v1.y, v1.z, v1.w};
#pragma unroll
            for (int k = 0; k < 8; ++k) {
                unsigned short h = bfr(vv[k]);
                rAh[k] = (short)h;
                rAl[k] = (short)bfr(vv[k] - bf2f(h));
            }
        }
#pragma unroll
        for (int p = 0; p < BP; ++p) {
            int id = p * 256 + tid;
            int r = id >> 2, c = id & 3;
            size_t offb = (size_t)(n0 + r) * KDIM + kb + c * 8;
            rBh[p] = *(const short8*)(BThi + offb);
            rBl[p] = *(const short8*)(BTlo + offb);
        }
    };
    auto STORE = [&]() {
        {
            int r = tid >> 2, c = tid & 3;
            *(short8*)(&As_hi[r * BK + c * 8]) = rAh;
            *(short8*)(&As_lo[r * BK + c * 8]) = rAl;
        }
#pragma unroll
        for (int p = 0; p < BP; ++p) {
            int id = p * 256 + tid;
            int r = id >> 2, c = id & 3;
            *(short8*)(&Bs_hi[r * BK + c * 8]) = rBh[p];
            *(short8*)(&Bs_lo[r * BK + c * 8]) = rBl[p];
        }
    };

    constexpr int NT = KDIM / BK;
    LOAD(0);
    for (int t = 0; t < NT; ++t) {
        STORE();
        __syncthreads();
        if (t + 1 < NT) LOAD((t + 1) * BK);

        short8 afh[FR], afl[FR], bfh[FC], bfl[FC];
#pragma unroll
        for (int fr = 0; fr < FR; ++fr) {
            int r = wr * WROWS + fr * 16 + lrow;
            afh[fr] = *(const short8*)(&As_hi[r * BK + lk * 8]);
            afl[fr] = *(const short8*)(&As_lo[r * BK + lk * 8]);
        }
#pragma unroll
        for (int fc = 0; fc < FC; ++fc) {
            int r = wc * WCOLS + fc * 16 + lrow;
            bfh[fc] = *(const short8*)(&Bs_hi[r * BK + lk * 8]);
            bfl[fc] = *(const short8*)(&Bs_lo[r * BK + lk * 8]);
        }
#pragma unroll
        for (int fr = 0; fr < FR; ++fr)
#pragma unroll
            for (int fc = 0; fc < FC; ++fc) {
                acc[fr][fc] = __builtin_amdgcn_mfma_f32_16x16x32_bf16(afh[fr], bfh[fc], acc[fr][fc], 0, 0, 0);
                acc[fr][fc] = __builtin_amdgcn_mfma_f32_16x16x32_bf16(afh[fr], bfl[fc], acc[fr][fc], 0, 0, 0);
                acc[fr][fc] = __builtin_amdgcn_mfma_f32_16x16x32_bf16(afl[fr], bfh[fc], acc[fr][fc], 0, 0, 0);
            }
        __syncthreads();
    }

#pragma unroll
    for (int fr = 0; fr < FR; ++fr) {
        const int rbase = m0 + wr * WROWS + fr * 16 + lk * 4;
        float ps[4] = {0.f, 0.f, 0.f, 0.f}, pd[4] = {0.f, 0.f, 0.f, 0.f};
#pragma unroll
        for (int fc = 0; fc < FC; ++fc) {
            const int gc   = n0 + wc * WCOLS + fc * 16 + lrow;
            const int head = gc / CPH, ci = gc % CPH;
            const float asv = avec_s[head * CPH + ci];
            const float adv = avec_d[head * CPH + ci];
#pragma unroll
            for (int rg = 0; rg < 4; ++rg) {
                int row = rbase + rg;
                float v = acc[fr][fc][rg];
                unsigned short uh = bfr(v);
                unsigned up = (unsigned)__shfl_xor((int)(unsigned)uh, 1);
                if (!(lrow & 1) && row < M)
                    *(unsigned*)(Cb + (size_t)row * N + gc) = (unsigned)uh | (up << 16);
                ps[rg] += v * asv;
                pd[rg] += v * adv;
            }
        }
        const int head = (n0 + wc * WCOLS) / CPH;
#pragma unroll
        for (int rg = 0; rg < 4; ++rg) {
            float s = ps[rg], d = pd[rg];
#pragma unroll
            for (int m = 1; m <= 8; m <<= 1) {
                s += __shfl_xor(s, m);
                d += __shfl_xor(d, m);
            }
            if (lrow == 0 && rbase + rg < M) {
                alpha_s[(size_t)(rbase + rg) * HEADS + head] = s;
                alpha_d[(size_t)(rbase + rg) * HEADS + head] = d;
            }
        }
    }
}

// ---------------- MFMA GEMM template (layer 2) ----------------
template<int BM, int BN, int KDIM, int WR, int WC, int CPH, bool ALO>
__global__ __launch_bounds__(256, 2)
void mfma_gemm_gat(const unsigned short* __restrict__ Ahi, const unsigned short* __restrict__ Alo,
                   const unsigned short* __restrict__ BThi, const unsigned short* __restrict__ BTlo,
                   unsigned short* __restrict__ Cb,
                   const float* __restrict__ avec_s, const float* __restrict__ avec_d,
                   float* __restrict__ alpha_s, float* __restrict__ alpha_d,
                   int M, int N)
{
    constexpr int BK    = 32;
    constexpr int WROWS = BM / WR;
    constexpr int WCOLS = BN / WC;
    constexpr int FR    = WROWS / 16;
    constexpr int FC    = WCOLS / 16;
    constexpr int AP    = (BM * (BK / 8)) / 256;
    constexpr int BP    = (BN * (BK / 8)) / 256;
    static_assert(AP >= 1 && BP >= 1, "tile too small");

    __shared__ short As_hi[BM * BK], As_lo[ALO ? BM * BK : 64];
    __shared__ short Bs_hi[BN * BK], Bs_lo[BN * BK];

    const int tid  = threadIdx.x;
    const int w    = tid >> 6, lane = tid & 63;
    const int wr   = w / WC, wc = w % WC;
    const int lrow = lane & 15, lk = lane >> 4;
    const int m0   = blockIdx.x * BM, n0 = blockIdx.y * BN;

    f32x4 acc[FR][FC];
#pragma unroll
    for (int i = 0; i < FR; ++i)
#pragma unroll
        for (int j = 0; j < FC; ++j) acc[i][j] = (f32x4){0.f, 0.f, 0.f, 0.f};

    short8 rAh[AP], rAl[AP], rBh[BP], rBl[BP];

    auto LOAD = [&](int kb) {
#pragma unroll
        for (int p = 0; p < AP; ++p) {
            int id = p * 256 + tid;
            int r = id >> 2, c = id & 3;
            int row = m0 + r; row = row < M ? row : M - 1;
            size_t off = (size_t)row * KDIM + kb + c * 8;
            rAh[p] = *(const short8*)(Ahi + off);
            if constexpr (ALO) rAl[p] = *(const short8*)(Alo + off);
        }
#pragma unroll
        for (int p = 0; p < BP; ++p) {
            int id = p * 256 + tid;
            int r = id >> 2, c = id & 3;
            size_t off = (size_t)(n0 + r) * KDIM + kb + c * 8;
            rBh[p] = *(const short8*)(BThi + off);
            rBl[p] = *(const short8*)(BTlo + off);
        }
    };
    auto STORE = [&]() {
#pragma unroll
        for (int p = 0; p < AP; ++p) {
            int id = p * 256 + tid;
            int r = id >> 2, c = id & 3;
            *(short8*)(&As_hi[r * BK + c * 8]) = rAh[p];
            if constexpr (ALO) *(short8*)(&As_lo[r * BK + c * 8]) = rAl[p];
        }
#pragma unroll
        for (int p = 0; p < BP; ++p) {
            int id = p * 256 + tid;
            int r = id >> 2, c = id & 3;
            *(short8*)(&Bs_hi[r * BK + c * 8]) = rBh[p];
            *(short8*)(&Bs_lo[r * BK + c * 8]) = rBl[p];
        }
    };

    constexpr int NT = KDIM / BK;
    LOAD(0);
    for (int t = 0; t < NT; ++t) {
        STORE();
        __syncthreads();
        if (t + 1 < NT) LOAD((t + 1) * BK);

        short8 afh[FR], afl[FR], bfh[FC], bfl[FC];
#pragma unroll
        for (int fr = 0; fr < FR; ++fr) {
            int r = wr * WROWS + fr * 16 + lrow;
            afh[fr] = *(const short8*)(&As_hi[r * BK + lk * 8]);
            if constexpr (ALO) afl[fr] = *(const short8*)(&As_lo[r * BK + lk * 8]);
        }
#pragma unroll
        for (int fc = 0; fc < FC; ++fc) {
            int r = wc * WCOLS + fc * 16 + lrow;
            bfh[fc] = *(const short8*)(&Bs_hi[r * BK + lk * 8]);
            bfl[fc] = *(const short8*)(&Bs_lo[r * BK + lk * 8]);
        }
#pragma unroll
        for (int fr = 0; fr < FR; ++fr)
#pragma unroll
            for (int fc = 0; fc < FC; ++fc) {
                acc[fr][fc] = __builtin_amdgcn_mfma_f32_16x16x32_bf16(afh[fr], bfh[fc], acc[fr][fc], 0, 0, 0);
                acc[fr][fc] = __builtin_amdgcn_mfma_f32_16x16x32_bf16(afh[fr], bfl[fc], acc[fr][fc], 0, 0, 0);
                if constexpr (ALO)
                    acc[fr][fc] = __builtin_amdgcn_mfma_f32_16x16x32_bf16(afl[fr], bfh[fc], acc[fr][fc], 0, 0, 0);
            }
        __syncthreads();
    }

#pragma unroll
    for (int fr = 0; fr < FR; ++fr) {
        const int rbase = m0 + wr * WROWS + fr * 16 + lk * 4;
        float ps[4] = {0.f, 0.f, 0.f, 0.f}, pd[4] = {0.f, 0.f, 0.f, 0.f};
#pragma unroll
        for (int fc = 0; fc < FC; ++fc) {
            const int gc   = n0 + wc * WCOLS + fc * 16 + lrow;
            const int head = gc / CPH, ci = gc % CPH;
            const float asv = avec_s[head * CPH + ci];
            const float adv = avec_d[head * CPH + ci];
#pragma unroll
            for (int rg = 0; rg < 4; ++rg) {
                int row = rbase + rg;
                float v = acc[fr][fc][rg];
                unsigned short uh = bfr(v);
                unsigned up = (unsigned)__shfl_xor((int)(unsigned)uh, 1);
                if (!(lrow & 1) && row < M)
                    *(unsigned*)(Cb + (size_t)row * N + gc) = (unsigned)uh | (up << 16);
                ps[rg] += v * asv;
                pd[rg] += v * adv;
            }
            if constexpr (CPH == 16) {
#pragma unroll
                for (int rg = 0; rg < 4; ++rg) {
                    float s = ps[rg], d = pd[rg];
#pragma unroll
                    for (int m = 1; m <= 8; m <<= 1) {
                        s += __shfl_xor(s, m);
                        d += __shfl_xor(d, m);
                    }
                    if (lrow == 0 && rbase + rg < M) {
                        alpha_s[(size_t)(rbase + rg) * HEADS + head] = s;
                        alpha_d[(size_t)(rbase + rg) * HEADS + head] = d;
                    }
                    ps[rg] = 0.f; pd[rg] = 0.f;
                }
            }
        }
        if constexpr (CPH != 16) {
            const int head = (n0 + wc * WCOLS) / CPH;
#pragma unroll
            for (int rg = 0; rg < 4; ++rg) {
                float s = ps[rg], d = pd[rg];
#pragma unroll
                for (int m = 1; m <= 8; m <<= 1) {
                    s += __shfl_xor(s, m);
                    d += __shfl_xor(d, m);
                }
                if (lrow == 0 && rbase + rg < M) {
                    alpha_s[(size_t)(rbase + rg) * HEADS + head] = s;
                    alpha_d[(size_t)(rbase + rg) * HEADS + head] = d;
                }
            }
        }
    }
}

// ---------------- GAT softmax + aggregation (bucket CSR) ----------------
template<int CH, int S, bool OUTF32>
__global__ __launch_bounds__(256)
void gat_agg(const unsigned short* __restrict__ hb, const float* __restrict__ alpha_s,
             const float* __restrict__ alpha_d, const int* __restrict__ cnt,
             const int* __restrict__ csr, const float* __restrict__ bias,
             float* __restrict__ out, unsigned short* __restrict__ out_hi, int n)
{
    constexpr int CPL = CH / S;
    constexpr int NSG = 256 / S;
    static_assert(CPL == 8, "lane owns one uint4");
    __shared__ float wls[NSG][S * 5];
    const int tid    = threadIdx.x;
    const int sub    = tid / S;
    const int i      = tid % S;
    const int lane64 = tid & 63;
    const int base   = lane64 & ~(S - 1);
    const int node   = blockIdx.x * NSG + sub;
    if (node >= n) return;
    const int head = (i * CPL) / (CH / 4);
    const int deg = min(cnt[node], CAP);
    const size_t ebase = (size_t)node * CAP;

    const float4 asn = *(const float4*)(alpha_s + (size_t)node * 4);
    const float4 adn = *(const float4*)(alpha_d + (size_t)node * 4);
    float4 den = f4exp(f4lrelu(f4add(asn, adn)));
    const float wse = pickh(den, head);

    float acc[8];
    {
        uint4 hv = *(const uint4*)(hb + (size_t)node * CH + i * 8);
        float2 q0 = bfpair(hv.x), q1 = bfpair(hv.y), q2 = bfpair(hv.z), q3 = bfpair(hv.w);
        acc[0] = wse * q0.x; acc[1] = wse * q0.y; acc[2] = wse * q1.x; acc[3] = wse * q1.y;
        acc[4] = wse * q2.x; acc[5] = wse * q2.y; acc[6] = wse * q3.x; acc[7] = wse * q3.y;
    }

    for (int ch = 0; ch < deg; ch += S) {
        const int cntc = min(S, deg - ch);
        float4 w4 = make_float4(0.f, 0.f, 0.f, 0.f);
        int sl = 0;
        if (i < cntc) {
            sl = csr[ebase + ch + i];
            float4 al = *(const float4*)(alpha_s + (size_t)sl * 4);
            w4 = f4exp(f4lrelu(f4add(al, adn)));
        }
        float4 t = w4;
#pragma unroll
        for (int d = S / 2; d >= 1; d >>= 1) {
            t.x += __shfl_xor(t.x, d);
            t.y += __shfl_xor(t.y, d);
            t.z += __shfl_xor(t.z, d);
            t.w += __shfl_xor(t.w, d);
        }
        den = f4add(den, t);
        wls[sub][i * 5 + 0] = w4.x;
        wls[sub][i * 5 + 1] = w4.y;
        wls[sub][i * 5 + 2] = w4.z;
        wls[sub][i * 5 + 3] = w4.w;

        const int padded = (cntc + 7) & ~7;
        for (int j = 0; j < padded; j += 8) {
            int   sk[8];
            float wk[8];
#pragma unroll
            for (int k = 0; k < 8; ++k) {
                sk[k] = __shfl(sl, base + ((j + k) < S ? (j + k) : 0));
                wk[k] = wls[sub][(j + k) * 5 + head];
            }
            uint4 v[8];
#pragma unroll
            for (int k = 0; k < 8; ++k)
                v[k] = *(const uint4*)(hb + (size_t)sk[k] * CH + i * 8);
#pragma unroll
            for (int k = 0; k < 8; ++k) {
                float2 q0 = bfpair(v[k].x), q1 = bfpair(v[k].y);
                float2 q2 = bfpair(v[k].z), q3 = bfpair(v[k].w);
                acc[0] += wk[k] * q0.x; acc[1] += wk[k] * q0.y;
                acc[2] += wk[k] * q1.x; acc[3] += wk[k] * q1.y;
                acc[4] += wk[k] * q2.x; acc[5] += wk[k] * q2.y;
                acc[6] += wk[k] * q3.x; acc[7] += wk[k] * q3.y;
            }
        }
    }

    const float invd = 1.0f / (pickh(den, head) + 1e-16f);
    const int c0 = i * CPL;
    float o[8];
#pragma unroll
    for (int k = 0; k < 8; ++k)
        o[k] = fmaxf(acc[k] * invd + bias[c0 + k], 0.f);
    if constexpr (OUTF32) {
        *(float4*)(out + (size_t)node * CH + c0)     = make_float4(o[0], o[1], o[2], o[3]);
        *(float4*)(out + (size_t)node * CH + c0 + 4) = make_float4(o[4], o[5], o[6], o[7]);
    } else {
        unsigned short oh[8];
#pragma unroll
        for (int k = 0; k < 8; ++k) oh[k] = bfr(o[k]);
        uint4 ph;
        ph.x = (unsigned)oh[0] | ((unsigned)oh[1] << 16);
        ph.y = (unsigned)oh[2] | ((unsigned)oh[3] << 16);
        ph.z = (unsigned)oh[4] | ((unsigned)oh[5] << 16);
        ph.w = (unsigned)oh[6] | ((unsigned)oh[7] << 16);
        *(uint4*)(out_hi + (size_t)node * CH + c0) = ph;
    }
}

// ---------------- fused mean-pool/FC (per-block binary search) ----------------
__global__ __launch_bounds__(256)
void pool_fc_kernel(const float* __restrict__ feat, const int* __restrict__ batch,
                    const float* __restrict__ Wfc, const float* __restrict__ bfc,
                    float* __restrict__ out, int n)
{
    __shared__ float4 part[16][16];
    __shared__ float pooled[64];
    __shared__ int sb[2];
    const int g = blockIdx.x;
    const int t = threadIdx.x;
    if (t < 2) {
        int target = g + t;
        int lo = 0, hi = n;
        while (lo < hi) {
            int mid = (lo + hi) >> 1;
            if (batch[mid] < target) lo = mid + 1; else hi = mid;
        }
        sb[t] = lo;
    }
    __syncthreads();
    const int s0 = sb[0], s1 = sb[1];
    const int q = t & 15, ns = t >> 4;
    float4 acc = make_float4(0.f, 0.f, 0.f, 0.f);
    for (int i = s0 + ns; i < s1; i += 16)
        acc = f4add(acc, *(const float4*)(feat + (size_t)i * 64 + q * 4));
    part[ns][q] = acc;
    __syncthreads();
    if (t < 16) {
        float4 s = part[0][t];
#pragma unroll
        for (int k = 1; k < 16; ++k) s = f4add(s, part[k][t]);
        float inv = 1.0f / fmaxf((float)(s1 - s0), 1.0f);
        pooled[t * 4 + 0] = s.x * inv;
        pooled[t * 4 + 1] = s.y * inv;
        pooled[t * 4 + 2] = s.z * inv;
        pooled[t * 4 + 3] = s.w * inv;
    }
    __syncthreads();
    if (t < 2) {
        float a = bfc[t];
        for (int c = 0; c < 64; ++c) a += pooled[c] * Wfc[c * 2 + t];
        out[g * 2 + t] = a;
    }
}

// ---------------- launch ----------------
extern "C" void kernel_launch(void* const* d_in, const int* in_sizes, int n_in,
                              void* d_out, int out_size, void* d_ws, size_t ws_size,
                              hipStream_t stream)
{
    const float* x    = (const float*)d_in[0];
    const int*   ei   = (const int*)d_in[1];
    const int*   batch= (const int*)d_in[2];
    const float* W1   = (const float*)d_in[3];
    const float* as1  = (const float*)d_in[4];
    const float* ad1  = (const float*)d_in[5];
    const float* b1   = (const float*)d_in[6];
    const float* W2   = (const float*)d_in[7];
    const float* as2  = (const float*)d_in[8];
    const float* ad2  = (const float*)d_in[9];
    const float* b2   = (const float*)d_in[10];
    const float* Wfc  = (const float*)d_in[11];
    const float* bfc  = (const float*)d_in[12];
    float* out = (float*)d_out;

    const int N = in_sizes[2];          // 50000 nodes
    const int E = in_sizes[1] / 27;     // 400000 edges
    const int F = in_sizes[0] / N;      // 128
    (void)F;

    char* ws = (char*)d_ws;
    unsigned short* h1b   = (unsigned short*)(ws + OFF_H1B);
    unsigned short* h2b   = (unsigned short*)(ws + OFF_H2B);
    float*          out2  = (float*)(ws + OFF_OUT2);
    unsigned short* o1hi  = (unsigned short*)(ws + OFF_O1HI);
    unsigned short* w1th  = (unsigned short*)(ws + OFF_W1TH);
    unsigned short* w1tl  = (unsigned short*)(ws + OFF_W1TL);
    unsigned short* w2th  = (unsigned short*)(ws + OFF_W2TH);
    unsigned short* w2tl  = (unsigned short*)(ws + OFF_W2TL);
    float* al_s  = (float*)(ws + OFF_AS);
    float* al_d  = (float*)(ws + OFF_AD);
    int*   cnt   = (int*)(ws + OFF_CNT);    // 2N counts (layer2 view = cnt+N)
    int*   csr   = (int*)(ws + OFF_CSR);    // 2N*CAP bucket table

    const int NCH = (2 * E + 2047) / 2048;         // 391 edge chunks (both layers)
    const int ZB  = ((2 * N / 4) + 255) / 256;     // 98 zero-blocks in prep
    const int GX  = (N + 63) / 64;                 // 782 gemm1 blocks per col-half
    const int GROUPS = ((GX * 2 + 7) / 8 > (NCH + 1) / 2) ? (GX * 2 + 7) / 8
                                                          : (NCH + 1) / 2;   // 196

    // ---- 1: prep (W splits + cnt zero) ----
    prep_kernel<<<192 + ZB, 256, 0, stream>>>(W1, w1th, w1tl, W2, w2th, w2tl, cnt, 2 * N);

    // ---- 2: FUSED+interleaved layer-1 GEMM (f32 x) || bucket build (both layers) ----
    gemm1_bucket_kernel<<<GROUPS * 24, 256, 0, stream>>>(
        x, w1th, w1tl, h1b, as1, ad1, al_s, al_d, N, HEADS * 64, GX, NCH,
        ei + 17 * (size_t)E, ei + 26 * (size_t)E,
        ei + 15 * (size_t)E, ei + 16 * (size_t)E,
        cnt, csr, N, E);

    // ---- 3: layer-1 aggregation (S=32, bf16 hi out) ----
    gat_agg<256, 32, false><<<(N + 7) / 8, 256, 0, stream>>>(h1b, al_s, al_d, cnt, csr, b1,
                                                             nullptr, o1hi, N);

    // ---- 4: layer-2 MFMA GEMM (bf16 A, 2-pass) -> bf16 h2 ----
    {
        dim3 g((N + 63) / 64, 1);
        mfma_gemm_gat<64, 64, 256, 2, 2, 16, false><<<g, 256, 0, stream>>>(
            o1hi, nullptr, w2th, w2tl, h2b, as2, ad2, al_s, al_d, N, HEADS * 16);
    }
    // ---- 5: layer-2 aggregation (S=8, 16B gathers, f32 out) ----
    gat_agg<64, 8, true><<<(N + 31) / 32, 256, 0, stream>>>(h2b, al_s, al_d, cnt + N,
                                                            csr + (size_t)N * CAP, b2,
                                                            out2, nullptr, N);

    // ---- 6: fused mean-pool + FC ----
    pool_fc_kernel<<<64, 256, 0, stream>>>(out2, batch, Wfc, bfc, out, N);
}